// Round 1
// baseline (110.344 us; speedup 1.0000x reference)
//
#include <hip/hip_runtime.h>
#include <hip/hip_fp16.h>

// Problem constants (reference: D=128 vars, H=16 hidden, B=8192 batch)
#define DD 128
#define HH 16
#define BB 8192

typedef _Float16 half8 __attribute__((ext_vector_type(8)));
typedef _Float16 half4 __attribute__((ext_vector_type(4)));
typedef float f32x4 __attribute__((ext_vector_type(4)));

// ---------------------------------------------------------------------------
// Kernel 1: soft adjacency. softmax over {off,on} == sigmoid of logit diff.
// A[v,i] = sigmoid((2*L[v,i] + g1 - g0)/T), diagonal zeroed. fp32 exact.
// ---------------------------------------------------------------------------
__global__ void k_adj(const float* __restrict__ L, const float* __restrict__ Tptr,
                      const float* __restrict__ g, float* __restrict__ Aout) {
    int idx = blockIdx.x * blockDim.x + threadIdx.x;   // idx = v*DD + i
    if (idx >= DD * DD) return;
    int v = idx >> 7;
    int i = idx & (DD - 1);
    float t = Tptr[0];
    float z = (2.0f * L[idx] + g[2 * idx + 1] - g[2 * idx]) / t;
    float a = 1.0f / (1.0f + __expf(-z));
    if (v == i) a = 0.0f;
    Aout[idx] = a;
}

// ---------------------------------------------------------------------------
// Kernel 2: X (fp32) -> Xh (f16), row-major [BB][DD]. float4 in, 8B out.
// ---------------------------------------------------------------------------
__global__ void k_xcvt(const float* __restrict__ X, _Float16* __restrict__ Xh) {
    int idx = (blockIdx.x * blockDim.x + threadIdx.x) * 4;
    float4 x = *(const float4*)(X + idx);
    half4 h;
    h[0] = (_Float16)x.x; h[1] = (_Float16)x.y;
    h[2] = (_Float16)x.z; h[3] = (_Float16)x.w;
    *(half4*)(Xh + idx) = h;
}

// ---------------------------------------------------------------------------
// Kernel 3: effective weights, transposed for MFMA B-fragment loads.
// Wt[i][h][v] = f16( A[v,i] * W1[i,v,h] ).  Layout [DD][HH][DD] contiguous in v
// so a lane's B-frag (8 consecutive k=v values at fixed n=h) is one 16B load.
// ---------------------------------------------------------------------------
__global__ void k_wt(const float* __restrict__ A, const float* __restrict__ W1,
                     _Float16* __restrict__ Wt) {
    int idx = blockIdx.x * blockDim.x + threadIdx.x;   // i*HH*DD + h*DD + v
    int v = idx & (DD - 1);
    int h = (idx >> 7) & (HH - 1);
    int i = idx >> 11;
    Wt[idx] = (_Float16)(A[v * DD + i] * W1[(i * DD + v) * HH + h]);
}

// ---------------------------------------------------------------------------
// Main kernel. Block = 256 threads = 4 waves. Each wave: one 16-row batch
// tile x 16 variables i. Per i: hidden(16x16) = X_tile(16x128) @ Wt_i(128x16)
// via 4x mfma_f32_16x16x32_f16, then fp32 epilogue (bias, relu, *W2,
// shuffle-reduce over h, +b2) -> LDS -> coalesced float4 store.
// Fragment layouts (gfx950, 16x16x32): A: m=lane&15, k=quad*8+j.
// B: n=lane&15, k=quad*8+j. C/D: col=lane&15, row=quad*4+reg.
// ---------------------------------------------------------------------------
__launch_bounds__(256)
__global__ void k_main(const _Float16* __restrict__ Xh, const _Float16* __restrict__ Wt,
                       const float* __restrict__ b1, const float* __restrict__ W2,
                       const float* __restrict__ b2, float* __restrict__ out) {
    __shared__ float ltile[64 * 17];   // [64 rows][16 i] padded +1 vs banks

    const int tid  = threadIdx.x;
    const int wave = tid >> 6;
    const int lane = tid & 63;
    const int m    = lane & 15;        // A-row / B-col index
    const int q    = lane >> 4;        // quad

    const int b0 = blockIdx.x * 64 + wave * 16;   // batch tile base for this wave
    const int i0 = blockIdx.y * 16;               // variable group base

    // A-fragments: X rows, reused across all 16 i's.
    half8 xa[4];
    const _Float16* xp = Xh + (b0 + m) * DD + q * 8;
#pragma unroll
    for (int s = 0; s < 4; s++) xa[s] = *(const half8*)(xp + s * 32);

    for (int ii = 0; ii < 16; ii++) {
        const int i = i0 + ii;
        f32x4 acc = {0.f, 0.f, 0.f, 0.f};
        const _Float16* wp = Wt + (i * HH + m) * DD + q * 8;
#pragma unroll
        for (int s = 0; s < 4; s++) {
            half8 wb = *(const half8*)(wp + s * 32);
            acc = __builtin_amdgcn_mfma_f32_16x16x32_f16(xa[s], wb, acc, 0, 0, 0);
        }
        // Epilogue in fp32. Lane holds hidden[row=q*4+r][h=m] for r=0..3.
        const float b1v = b1[i * HH + m];
        const float w2v = W2[i * HH + m];
        float vr[4];
#pragma unroll
        for (int r = 0; r < 4; r++) {
            float t = acc[r] + b1v;
            t = t > 0.0f ? t : 0.0f;
            vr[r] = t * w2v;
        }
        // Butterfly sum over the 16-lane h-group (masks 1,2,4,8 stay in-group).
#pragma unroll
        for (int mask = 1; mask < 16; mask <<= 1) {
#pragma unroll
            for (int r = 0; r < 4; r++) vr[r] += __shfl_xor(vr[r], mask, 64);
        }
        if (m == 0) {
            const float b2v = b2[i];
#pragma unroll
            for (int r = 0; r < 4; r++)
                ltile[(wave * 16 + q * 4 + r) * 17 + ii] = vr[r] + b2v;
        }
    }
    __syncthreads();

    // Coalesced block store: 64 rows x 16 i = 1024 floats, 4 per thread.
    const int row = tid >> 2;
    const int c4  = (tid & 3) * 4;
    float4 o;
    o.x = ltile[row * 17 + c4 + 0];
    o.y = ltile[row * 17 + c4 + 1];
    o.z = ltile[row * 17 + c4 + 2];
    o.w = ltile[row * 17 + c4 + 3];
    *(float4*)(out + (blockIdx.x * 64 + row) * DD + i0 + c4) = o;
}

// ---------------------------------------------------------------------------
extern "C" void kernel_launch(void* const* d_in, const int* in_sizes, int n_in,
                              void* d_out, int out_size, void* d_ws, size_t ws_size,
                              hipStream_t stream) {
    const float* X  = (const float*)d_in[0];
    const float* L  = (const float*)d_in[1];
    const float* T  = (const float*)d_in[2];
    const float* g  = (const float*)d_in[3];
    const float* W1 = (const float*)d_in[4];
    const float* b1 = (const float*)d_in[5];
    const float* W2 = (const float*)d_in[6];
    const float* b2 = (const float*)d_in[7];

    float* recon = (float*)d_out;              // output 0: [BB, DD]
    float* Aout  = recon + (size_t)BB * DD;    // output 1: [DD, DD]

    _Float16* Xh = (_Float16*)d_ws;            // [BB][DD] f16, 2 MB
    _Float16* Wt = Xh + (size_t)BB * DD;       // [DD][HH][DD] f16, 512 KB

    k_adj <<<(DD * DD) / 256, 256, 0, stream>>>(L, T, g, Aout);
    k_xcvt<<<(BB * DD / 4) / 256, 256, 0, stream>>>(X, Xh);
    k_wt  <<<(DD * HH * DD) / 256, 256, 0, stream>>>(Aout, W1, Wt);

    dim3 grid(BB / 64, DD / 16);
    k_main<<<grid, 256, 0, stream>>>(Xh, Wt, b1, W2, b2, recon);
}

// Round 2
// 107.628 us; speedup vs baseline: 1.0252x; 1.0252x over previous
//
#include <hip/hip_runtime.h>
#include <hip/hip_fp16.h>

// Problem constants (reference: D=128 vars, H=16 hidden, B=8192 batch)
#define DD 128
#define HH 16
#define BB 8192

typedef _Float16 half8 __attribute__((ext_vector_type(8)));
typedef float f32x4 __attribute__((ext_vector_type(4)));

// ---------------------------------------------------------------------------
// Fused prep: adjacency + effective weights.
//   A[v,i] = sigmoid((2*L[v,i] + g1 - g0)/T), diag zeroed   (fp32 exact)
//   Wt[i][h][v] = f16( A[v,i] * W1[i,v,h] )                 (B-frag layout)
// Thread map: idx = i*HH*DD + h*DD + v (v fastest -> coalesced Wt writes).
// Sigmoid recomputed HH times per (v,i) -- cheaper than a dispatch. h==0
// threads also write Aout (output 1).
// ---------------------------------------------------------------------------
__global__ void k_prep(const float* __restrict__ L, const float* __restrict__ Tptr,
                       const float* __restrict__ g, const float* __restrict__ W1,
                       float* __restrict__ Aout, _Float16* __restrict__ Wt) {
    int idx = blockIdx.x * blockDim.x + threadIdx.x;   // i*HH*DD + h*DD + v
    int v = idx & (DD - 1);
    int h = (idx >> 7) & (HH - 1);
    int i = idx >> 11;
    int vi = v * DD + i;
    float t = Tptr[0];
    float z = (2.0f * L[vi] + g[2 * vi + 1] - g[2 * vi]) / t;
    float a = 1.0f / (1.0f + __expf(-z));
    if (v == i) a = 0.0f;
    if (h == 0) Aout[vi] = a;
    Wt[idx] = (_Float16)(a * W1[(i * DD + v) * HH + h]);
}

// ---------------------------------------------------------------------------
// Main kernel. Block = 256 threads = 4 waves. Each wave: one 16-row batch
// tile x 16 variables i. X is read fp32 and converted to f16 in-register
// (A-fragments built once, reused across all 16 i's). Per i:
// hidden(16x16) = X_tile(16x128) @ Wt_i(128x16) via 4x mfma_f32_16x16x32_f16,
// then fp32 epilogue (bias, relu, *W2, 4-stage shuffle butterfly over the
// 16-lane h-group, +b2) -> LDS -> coalesced float4 store.
// Fragment layouts (gfx950, 16x16x32): A: m=lane&15, k=quad*8+j.
// B: n=lane&15, k=quad*8+j. C/D: col=lane&15, row=quad*4+reg.
// ---------------------------------------------------------------------------
__launch_bounds__(256)
__global__ void k_main(const float* __restrict__ X, const _Float16* __restrict__ Wt,
                       const float* __restrict__ b1, const float* __restrict__ W2,
                       const float* __restrict__ b2, float* __restrict__ out) {
    __shared__ float ltile[64 * 17];   // [64 rows][16 i] padded +1 vs banks

    const int tid  = threadIdx.x;
    const int wave = tid >> 6;
    const int lane = tid & 63;
    const int m    = lane & 15;        // A-row / B-col index
    const int q    = lane >> 4;        // quad

    const int b0 = blockIdx.x * 64 + wave * 16;   // batch tile base for this wave
    const int i0 = blockIdx.y * 16;               // variable group base

    // A-fragments: X rows fp32 -> f16, built once, reused across all 16 i's.
    half8 xa[4];
    const float* xp = X + (b0 + m) * DD + q * 8;
#pragma unroll
    for (int s = 0; s < 4; s++) {
        f32x4 lo = *(const f32x4*)(xp + s * 32);
        f32x4 hi = *(const f32x4*)(xp + s * 32 + 4);
        half8 hfrag;
        hfrag[0] = (_Float16)lo[0]; hfrag[1] = (_Float16)lo[1];
        hfrag[2] = (_Float16)lo[2]; hfrag[3] = (_Float16)lo[3];
        hfrag[4] = (_Float16)hi[0]; hfrag[5] = (_Float16)hi[1];
        hfrag[6] = (_Float16)hi[2]; hfrag[7] = (_Float16)hi[3];
        xa[s] = hfrag;
    }

#pragma unroll 2
    for (int ii = 0; ii < 16; ii++) {
        const int i = i0 + ii;
        f32x4 acc = {0.f, 0.f, 0.f, 0.f};
        const _Float16* wp = Wt + (i * HH + m) * DD + q * 8;
#pragma unroll
        for (int s = 0; s < 4; s++) {
            half8 wb = *(const half8*)(wp + s * 32);
            acc = __builtin_amdgcn_mfma_f32_16x16x32_f16(xa[s], wb, acc, 0, 0, 0);
        }
        // Epilogue in fp32. Lane holds hidden[row=q*4+r][h=m] for r=0..3.
        const float b1v = b1[i * HH + m];
        const float w2v = W2[i * HH + m];
        float vr[4];
#pragma unroll
        for (int r = 0; r < 4; r++) {
            float t = acc[r] + b1v;
            t = t > 0.0f ? t : 0.0f;
            vr[r] = t * w2v;
        }
        // Butterfly sum over the 16-lane h-group (masks 1,2,4,8 stay in-group).
#pragma unroll
        for (int mask = 1; mask < 16; mask <<= 1) {
#pragma unroll
            for (int r = 0; r < 4; r++) vr[r] += __shfl_xor(vr[r], mask, 64);
        }
        if (m == 0) {
            const float b2v = b2[i];
#pragma unroll
            for (int r = 0; r < 4; r++)
                ltile[(wave * 16 + q * 4 + r) * 17 + ii] = vr[r] + b2v;
        }
    }
    __syncthreads();

    // Coalesced block store: 64 rows x 16 i = 1024 floats, 4 per thread.
    const int row = tid >> 2;
    const int c4  = (tid & 3) * 4;
    float4 o;
    o.x = ltile[row * 17 + c4 + 0];
    o.y = ltile[row * 17 + c4 + 1];
    o.z = ltile[row * 17 + c4 + 2];
    o.w = ltile[row * 17 + c4 + 3];
    *(float4*)(out + (blockIdx.x * 64 + row) * DD + i0 + c4) = o;
}

// ---------------------------------------------------------------------------
extern "C" void kernel_launch(void* const* d_in, const int* in_sizes, int n_in,
                              void* d_out, int out_size, void* d_ws, size_t ws_size,
                              hipStream_t stream) {
    const float* X  = (const float*)d_in[0];
    const float* L  = (const float*)d_in[1];
    const float* T  = (const float*)d_in[2];
    const float* g  = (const float*)d_in[3];
    const float* W1 = (const float*)d_in[4];
    const float* b1 = (const float*)d_in[5];
    const float* W2 = (const float*)d_in[6];
    const float* b2 = (const float*)d_in[7];

    float* recon = (float*)d_out;              // output 0: [BB, DD]
    float* Aout  = recon + (size_t)BB * DD;    // output 1: [DD, DD]

    _Float16* Wt = (_Float16*)d_ws;            // [DD][HH][DD] f16, 512 KB

    k_prep<<<(DD * HH * DD) / 256, 256, 0, stream>>>(L, T, g, W1, Aout, Wt);

    dim3 grid(BB / 64, DD / 16);
    k_main<<<grid, 256, 0, stream>>>(X, Wt, b1, W2, b2, recon);
}

// Round 4
// 93.191 us; speedup vs baseline: 1.1841x; 1.1549x over previous
//
#include <hip/hip_runtime.h>
#include <hip/hip_fp16.h>

// Problem constants (reference: D=128 vars, H=16 hidden, B=8192 batch)
#define DD 128
#define HH 16
#define BB 8192

typedef _Float16 half8 __attribute__((ext_vector_type(8)));
typedef _Float16 half4 __attribute__((ext_vector_type(4)));
typedef float f32x4 __attribute__((ext_vector_type(4)));

// ---------------------------------------------------------------------------
// Fused prep: adjacency + effective weights.
//   A[v,i] = sigmoid((2*L[v,i] + g1 - g0)/T), diag zeroed   (fp32 exact)
//   Wt[i][h][v] = f16( A[v,i] * W1[i,v,h] )                 (MFMA frag layout)
// ---------------------------------------------------------------------------
__global__ void k_prep(const float* __restrict__ L, const float* __restrict__ Tptr,
                       const float* __restrict__ g, const float* __restrict__ W1,
                       float* __restrict__ Aout, _Float16* __restrict__ Wt) {
    int idx = blockIdx.x * blockDim.x + threadIdx.x;   // i*HH*DD + h*DD + v
    int v = idx & (DD - 1);
    int h = (idx >> 7) & (HH - 1);
    int i = idx >> 11;
    int vi = v * DD + i;
    float t = Tptr[0];
    float z = (2.0f * L[vi] + g[2 * vi + 1] - g[2 * vi]) / t;
    float a = 1.0f / (1.0f + __expf(-z));
    if (v == i) a = 0.0f;
    if (h == 0) Aout[vi] = a;
    Wt[idx] = (_Float16)(a * W1[(i * DD + v) * HH + h]);
}

// ---------------------------------------------------------------------------
// Main kernel, no LDS, no shuffles. Block = 256 thr = 4 waves; each wave:
// 32 batch rows (2 tiles of 16) x 16 variables.
//
// Stage 1 (per i): hidden^T = Wt_i(16h x 128v) @ X^T(128v x 16b) via
//   4x mfma_f32_16x16x32_f16 with A=Wt (m=h), B=X (n=b).
//   D1 layout: lane&15 = col = b, quad*4+reg = row = h.
// Stage 2: P = relu(hidden^T + b1) converted to f16 lands EXACTLY in the
//   A-fragment layout of mfma_f32_16x16x16f16 (m=b=lane&15, k=h=q*4+j).
//   Accumulate out[b][i] via one masked-column MFMA per i:
//   B2[h][n] = W2[i][h] * (n==ii), acc2 initialized with b2 broadcast.
//   D2 layout: lane&15 = col = ii, quad*4+reg = row = b.
// Each Wt fragment load feeds 2 MFMAs (2 batch tiles) -> L2 traffic halved.
// ---------------------------------------------------------------------------
__launch_bounds__(256)
__global__ void k_main(const float* __restrict__ X, const _Float16* __restrict__ Wt,
                       const float* __restrict__ b1, const float* __restrict__ W2,
                       const float* __restrict__ b2, float* __restrict__ out) {
    const int tid  = threadIdx.x;
    const int wave = tid >> 6;
    const int lane = tid & 63;
    const int m    = lane & 15;        // frag row/col index
    const int q    = lane >> 4;        // quad

    const int b0 = blockIdx.x * 128 + wave * 32;  // 32 batch rows per wave
    const int i0 = blockIdx.y * 16;               // variable group base

    // X fragments (B-operand): n=lane&15=b, k=q*8+j=v. fp32 -> f16 in-register.
    half8 xb[2][4];
#pragma unroll
    for (int t = 0; t < 2; t++) {
        const float* xp = X + (b0 + t * 16 + m) * DD + q * 8;
#pragma unroll
        for (int s = 0; s < 4; s++) {
            f32x4 lo = *(const f32x4*)(xp + s * 32);
            f32x4 hi = *(const f32x4*)(xp + s * 32 + 4);
            half8 hf;
            hf[0] = (_Float16)lo[0]; hf[1] = (_Float16)lo[1];
            hf[2] = (_Float16)lo[2]; hf[3] = (_Float16)lo[3];
            hf[4] = (_Float16)hi[0]; hf[5] = (_Float16)hi[1];
            hf[6] = (_Float16)hi[2]; hf[7] = (_Float16)hi[3];
            xb[t][s] = hf;
        }
    }

    // W2 column fragment: lane holds W2[i0+m][q*4+j] as f16 (reduction B-op).
    f32x4 w2f = *(const f32x4*)(W2 + (i0 + m) * HH + q * 4);
    half4 w2self;
    w2self[0] = (_Float16)w2f[0]; w2self[1] = (_Float16)w2f[1];
    w2self[2] = (_Float16)w2f[2]; w2self[3] = (_Float16)w2f[3];
    const half4 hzero = {(_Float16)0.f, (_Float16)0.f, (_Float16)0.f, (_Float16)0.f};

    // Output accumulators, b2 folded into init (col = lane&15 = ii -> b2[i0+m]).
    const float b2v = b2[i0 + m];
    f32x4 acc2[2];
    acc2[0] = (f32x4){b2v, b2v, b2v, b2v};
    acc2[1] = (f32x4){b2v, b2v, b2v, b2v};

    for (int ii = 0; ii < 16; ii++) {
        const int i = i0 + ii;
        const _Float16* wp = Wt + (i * HH + m) * DD + q * 8;
        f32x4 a0 = {0.f, 0.f, 0.f, 0.f};
        f32x4 a1 = {0.f, 0.f, 0.f, 0.f};
#pragma unroll
        for (int s = 0; s < 4; s++) {
            half8 wa = *(const half8*)(wp + s * 32);
            a0 = __builtin_amdgcn_mfma_f32_16x16x32_f16(wa, xb[0][s], a0, 0, 0, 0);
            a1 = __builtin_amdgcn_mfma_f32_16x16x32_f16(wa, xb[1][s], a1, 0, 0, 0);
        }
        // bias + relu + f16 pack; lane's 4 values are h = q*4 + r.
        f32x4 b1v = *(const f32x4*)(b1 + i * HH + q * 4);
        half4 p0, p1;
#pragma unroll
        for (int r = 0; r < 4; r++) {
            float t0 = a0[r] + b1v[r];
            float t1 = a1[r] + b1v[r];
            p0[r] = (_Float16)(t0 > 0.f ? t0 : 0.f);
            p1[r] = (_Float16)(t1 > 0.f ? t1 : 0.f);
        }
        // Masked-column reduction MFMA: only column ii nonzero.
        half4 bfrag = (m == ii) ? w2self : hzero;
        acc2[0] = __builtin_amdgcn_mfma_f32_16x16x16f16(p0, bfrag, acc2[0], 0, 0, 0);
        acc2[1] = __builtin_amdgcn_mfma_f32_16x16x16f16(p1, bfrag, acc2[1], 0, 0, 0);
    }

    // Store: lane holds out[b = b0 + t*16 + q*4 + r][i0 + m].
#pragma unroll
    for (int t = 0; t < 2; t++)
#pragma unroll
        for (int r = 0; r < 4; r++)
            out[(size_t)(b0 + t * 16 + q * 4 + r) * DD + i0 + m] = acc2[t][r];
}

// ---------------------------------------------------------------------------
extern "C" void kernel_launch(void* const* d_in, const int* in_sizes, int n_in,
                              void* d_out, int out_size, void* d_ws, size_t ws_size,
                              hipStream_t stream) {
    const float* X  = (const float*)d_in[0];
    const float* L  = (const float*)d_in[1];
    const float* T  = (const float*)d_in[2];
    const float* g  = (const float*)d_in[3];
    const float* W1 = (const float*)d_in[4];
    const float* b1 = (const float*)d_in[5];
    const float* W2 = (const float*)d_in[6];
    const float* b2 = (const float*)d_in[7];

    float* recon = (float*)d_out;              // output 0: [BB, DD]
    float* Aout  = recon + (size_t)BB * DD;    // output 1: [DD, DD]

    _Float16* Wt = (_Float16*)d_ws;            // [DD][HH][DD] f16, 512 KB

    k_prep<<<(DD * HH * DD) / 256, 256, 0, stream>>>(L, T, g, W1, Aout, Wt);

    dim3 grid(BB / 128, DD / 16);
    k_main<<<grid, 256, 0, stream>>>(X, Wt, b1, W2, b2, recon);
}

// Round 6
// 89.494 us; speedup vs baseline: 1.2330x; 1.0413x over previous
//
#include <hip/hip_runtime.h>
#include <hip/hip_fp16.h>

// Problem constants (reference: D=128 vars, H=16 hidden, B=8192 batch)
#define DD 128
#define HH 16
#define BB 8192

typedef _Float16 hf8 __attribute__((ext_vector_type(8)));
typedef _Float16 hf4 __attribute__((ext_vector_type(4)));
typedef _Float16 hf2 __attribute__((ext_vector_type(2)));
typedef float f32x4 __attribute__((ext_vector_type(4)));

// packed f32->f16 (RTZ), bit-cast from the builtin's __fp16-based vector type
static __device__ __forceinline__ hf2 pkrtz(float a, float b) {
    return __builtin_bit_cast(hf2, __builtin_amdgcn_cvt_pkrtz(a, b));
}

// ---------------------------------------------------------------------------
// Fused prep: adjacency + effective weights.
//   A[v,i] = sigmoid((2*L[v,i] + g1 - g0)/T), diag zeroed   (fp32 exact)
//   Wt[i][h][v] = f16( A[v,i] * W1[i,v,h] )                 (MFMA frag layout)
// ---------------------------------------------------------------------------
__global__ void k_prep(const float* __restrict__ L, const float* __restrict__ Tptr,
                       const float* __restrict__ g, const float* __restrict__ W1,
                       float* __restrict__ Aout, _Float16* __restrict__ Wt) {
    int idx = blockIdx.x * blockDim.x + threadIdx.x;   // i*HH*DD + h*DD + v
    int v = idx & (DD - 1);
    int h = (idx >> 7) & (HH - 1);
    int i = idx >> 11;
    int vi = v * DD + i;
    float t = Tptr[0];
    float z = (2.0f * L[vi] + g[2 * vi + 1] - g[2 * vi]) / t;
    float a = 1.0f / (1.0f + __expf(-z));
    if (v == i) a = 0.0f;
    if (h == 0) Aout[vi] = a;
    Wt[idx] = (_Float16)(a * W1[(i * DD + v) * HH + h]);
}

// ---------------------------------------------------------------------------
// Main kernel, no LDS, no shuffles. Block = 128 thr = 2 waves; each wave:
// 64 batch rows (4 tiles of 16) x 16 variables -- each Wt fragment load
// feeds 4 MFMAs (Wt L2 traffic: 64 MB total).
//
// Stage 1 (per i): hidden^T = Wt_i(16h x 128v) @ X^T(128v x 16b) via
//   mfma_f32_16x16x32_f16 with A=Wt (m=h), B=X (n=b).
//   acc init = b1 broadcast (D reg r <-> row h=q*4+r) -- bias folded, free.
// Stage 2: P = relu(hidden^T) packed to f16 via v_cvt_pkrtz lands exactly in
//   the A-fragment layout of mfma_f32_16x16x16f16 (m=b=lane&15, k=h=q*4+j).
//   Masked-column MFMA per i accumulates out[b][i]; b2 folded into acc init.
// ---------------------------------------------------------------------------
__launch_bounds__(128)
__global__ void k_main(const float* __restrict__ X, const _Float16* __restrict__ Wt,
                       const float* __restrict__ b1, const float* __restrict__ W2,
                       const float* __restrict__ b2, float* __restrict__ out) {
    const int tid  = threadIdx.x;
    const int wave = tid >> 6;
    const int lane = tid & 63;
    const int m    = lane & 15;        // frag row/col index
    const int q    = lane >> 4;        // quad

    const int b0 = blockIdx.x * 128 + wave * 64;  // 64 batch rows per wave
    const int i0 = blockIdx.y * 16;               // variable group base

    // X fragments (B-operand): n=lane&15=b, k=q*8+j=v. fp32 -> f16 packed cvt.
    hf8 xb[4][4];
#pragma unroll
    for (int t = 0; t < 4; t++) {
        const float* xp = X + (size_t)(b0 + t * 16 + m) * DD + q * 8;
#pragma unroll
        for (int s = 0; s < 4; s++) {
            f32x4 lo = *(const f32x4*)(xp + s * 32);
            f32x4 hi = *(const f32x4*)(xp + s * 32 + 4);
            hf2 p0 = pkrtz(lo[0], lo[1]);
            hf2 p1 = pkrtz(lo[2], lo[3]);
            hf2 p2 = pkrtz(hi[0], hi[1]);
            hf2 p3 = pkrtz(hi[2], hi[3]);
            hf4 l4 = __builtin_shufflevector(p0, p1, 0, 1, 2, 3);
            hf4 h4 = __builtin_shufflevector(p2, p3, 0, 1, 2, 3);
            xb[t][s] = __builtin_shufflevector(l4, h4, 0, 1, 2, 3, 4, 5, 6, 7);
        }
    }

    // W2 column fragment: lane holds W2[i0+m][q*4+j] as f16 (reduction B-op).
    f32x4 w2f = *(const f32x4*)(W2 + (i0 + m) * HH + q * 4);
    hf2 wlo = pkrtz(w2f[0], w2f[1]);
    hf2 whi = pkrtz(w2f[2], w2f[3]);
    hf4 w2self = __builtin_shufflevector(wlo, whi, 0, 1, 2, 3);
    const hf4 hzero = {(_Float16)0.f, (_Float16)0.f, (_Float16)0.f, (_Float16)0.f};

    // Output accumulators, b2 folded into init (col = lane&15 = ii -> b2[i0+m]).
    const float b2v = b2[i0 + m];
    f32x4 acc2[4];
#pragma unroll
    for (int t = 0; t < 4; t++) acc2[t] = (f32x4){b2v, b2v, b2v, b2v};

#pragma unroll 2
    for (int ii = 0; ii < 16; ii++) {
        const int i = i0 + ii;
        const _Float16* wp = Wt + (i * HH + m) * DD + q * 8;
        // acc init = b1 (D reg r <-> row h = q*4+r), same for all batch tiles.
        f32x4 b1v = *(const f32x4*)(b1 + i * HH + q * 4);
        f32x4 a[4] = {b1v, b1v, b1v, b1v};
#pragma unroll
        for (int s = 0; s < 4; s++) {
            hf8 wa = *(const hf8*)(wp + s * 32);
#pragma unroll
            for (int t = 0; t < 4; t++)
                a[t] = __builtin_amdgcn_mfma_f32_16x16x32_f16(wa, xb[t][s], a[t], 0, 0, 0);
        }
        // relu + packed f16 cvt; lane's 4 values are h = q*4 + r.
        hf4 bfrag = (m == ii) ? w2self : hzero;
#pragma unroll
        for (int t = 0; t < 4; t++) {
            hf2 plo = pkrtz(__builtin_fmaxf(a[t][0], 0.f),
                            __builtin_fmaxf(a[t][1], 0.f));
            hf2 phi = pkrtz(__builtin_fmaxf(a[t][2], 0.f),
                            __builtin_fmaxf(a[t][3], 0.f));
            hf4 p = __builtin_shufflevector(plo, phi, 0, 1, 2, 3);
            acc2[t] = __builtin_amdgcn_mfma_f32_16x16x16f16(p, bfrag, acc2[t], 0, 0, 0);
        }
    }

    // Store: lane holds out[b = b0 + t*16 + q*4 + r][i0 + m].
#pragma unroll
    for (int t = 0; t < 4; t++)
#pragma unroll
        for (int r = 0; r < 4; r++)
            out[(size_t)(b0 + t * 16 + q * 4 + r) * DD + i0 + m] = acc2[t][r];
}

// ---------------------------------------------------------------------------
extern "C" void kernel_launch(void* const* d_in, const int* in_sizes, int n_in,
                              void* d_out, int out_size, void* d_ws, size_t ws_size,
                              hipStream_t stream) {
    const float* X  = (const float*)d_in[0];
    const float* L  = (const float*)d_in[1];
    const float* T  = (const float*)d_in[2];
    const float* g  = (const float*)d_in[3];
    const float* W1 = (const float*)d_in[4];
    const float* b1 = (const float*)d_in[5];
    const float* W2 = (const float*)d_in[6];
    const float* b2 = (const float*)d_in[7];

    float* recon = (float*)d_out;              // output 0: [BB, DD]
    float* Aout  = recon + (size_t)BB * DD;    // output 1: [DD, DD]

    _Float16* Wt = (_Float16*)d_ws;            // [DD][HH][DD] f16, 512 KB

    k_prep<<<(DD * HH * DD) / 256, 256, 0, stream>>>(L, T, g, W1, Aout, Wt);

    dim3 grid(BB / 128, DD / 16);               // 512 blocks x 2 waves
    k_main<<<grid, 128, 0, stream>>>(X, Wt, b1, W2, b2, recon);
}